// Round 7
// baseline (239.379 us; speedup 1.0000x reference)
//
#include <hip/hip_runtime.h>
#include <hip/hip_bf16.h>

typedef __bf16 bf16x8 __attribute__((ext_vector_type(8)));
typedef float f32x4 __attribute__((ext_vector_type(4)));
typedef float f32x4a __attribute__((ext_vector_type(4), aligned(4)));
typedef float f32x4u __attribute__((ext_vector_type(4), aligned(4)));
typedef unsigned short u16x8 __attribute__((ext_vector_type(8)));

typedef __attribute__((address_space(1))) const unsigned int gu32;
typedef __attribute__((address_space(3))) unsigned int lu32;

#define B_SZ   1024
#define IN_SZ  512
#define HID    128
#define OUT_SZ 64
#define BK     32
#define NKT    16        // K main loop = 512; j=512 handled as rank-1 tail
#define NTILES 2052      // 513 m-tiles x 4 n-tiles
#define GRID   512
#define ABUF   4096      // u16 per A buffer (128*32)
#define BBUF   8192      // u16 per B buffer (256*32)

static __device__ __forceinline__ unsigned short f2bf(float f) {
    __hip_bfloat16 h = __float2bfloat16(f);
    return *reinterpret_cast<unsigned short*>(&h);
}

// ---------------- prep: t_hat bf16 [1024][512], tc, xh natural [1024][513] --
__global__ __launch_bounds__(256) void prep_kernel(
    const float* __restrict__ img, const float* __restrict__ tab,
    unsigned short* __restrict__ tbt, float* __restrict__ xh,
    float* __restrict__ tc)
{
    const int blk = blockIdx.x;   // 0..1023
    for (int j = threadIdx.x; j < 512; j += 256) {
        float v = (j == 0) ? 1.0f : tab[(size_t)blk * IN_SZ + (j - 1)];
        tbt[(size_t)blk * 512 + j] = f2bf(v);
    }
    if (threadIdx.x == 0) tc[blk] = tab[(size_t)blk * IN_SZ + 511];
    for (int j = threadIdx.x; j < 513; j += 256)
        xh[(size_t)blk * 513 + j] =
            (j == 0) ? 1.0f : img[(size_t)blk * IN_SZ + (j - 1)];
}

// ---------------- prep2: W1 fp32 [65664][513] -> bf16 [65664][512] ----------
__global__ __launch_bounds__(256) void prep2_kernel(
    const float* __restrict__ w1, unsigned short* __restrict__ w1b)
{
    const long long gid = (long long)blockIdx.x * 256 + threadIdx.x;
    const int r  = (int)(gid >> 6);
    const int c8 = ((int)gid & 63) << 3;
    const float* src = w1 + (size_t)r * 513 + c8;
    const f32x4u lo = *reinterpret_cast<const f32x4u*>(src);
    const f32x4u hi = *reinterpret_cast<const f32x4u*>(src + 4);
    u16x8 u;
    u[0] = f2bf(lo[0]); u[1] = f2bf(lo[1]); u[2] = f2bf(lo[2]); u[3] = f2bf(lo[3]);
    u[4] = f2bf(hi[0]); u[5] = f2bf(hi[1]); u[6] = f2bf(hi[2]); u[7] = f2bf(hi[3]);
    *reinterpret_cast<u16x8*>(w1b + (size_t)r * 512 + c8) = u;
}

// ---------------- main fused GEMM: persistent blocks + work stealing --------
// BM=128, BN=256, BK=32. 8 waves, wave-grid 2M x 4N, wave-tile 64x64.
// 3-buf LDS, counted vmcnt(3), pipeline continuous across tiles.
__global__ __launch_bounds__(512, 4) void gemm_fused(
    const float* __restrict__ w1, const unsigned short* __restrict__ w1b,
    const unsigned short* __restrict__ tbt,
    const float* __restrict__ xh, const float* __restrict__ tc,
    float* __restrict__ y1acc, int* __restrict__ ctr)
{
    __shared__ unsigned short Als[3 * ABUF];   // 3 x 8 KB
    __shared__ unsigned short Bls[3 * BBUF];   // 3 x 16 KB
    __shared__ int sNxt;

    const int tid  = threadIdx.x;
    const int wv   = tid >> 6;
    const int wr   = wv >> 2;             // 0..1
    const int wc   = wv & 3;              // 0..3
    const int lane = tid & 63;
    const int l15  = lane & 15;
    const int kg   = lane >> 4;

    // A staging: phys chunk p = tid (128 rows x 4 chunks), source pre-swizzled
    const int ar  = tid >> 2;
    const int acl = (tid & 3) ^ ((ar >> 1) & 3);
    const size_t aRC = (size_t)ar * 512 + acl * 8;
    const int aBase = (wv * 64) * 8;      // wave-uniform dst (u16)

    // B staging: phys chunks p = q*512+tid (256 rows x 4 chunks)
    size_t bRC[2]; int bBase[2];
    #pragma unroll
    for (int q = 0; q < 2; ++q) {
        const int p  = q * 512 + tid;
        const int r  = p >> 2;
        const int cl = (p & 3) ^ ((r >> 1) & 3);
        bRC[q]   = (size_t)r * 512 + cl * 8;
        bBase[q] = (q * 512 + wv * 64) * 8;
    }

    // fragment read offsets (u16 units); phys chunk = kg ^ ((r>>1)&3)
    int aoffs[4], boffs[4];
    #pragma unroll
    for (int ms = 0; ms < 4; ++ms) {
        const int r = wr * 64 + ms * 16 + l15;
        aoffs[ms] = (r * 4 + (kg ^ ((r >> 1) & 3))) * 8;
    }
    #pragma unroll
    for (int ns = 0; ns < 4; ++ns) {
        const int r = wc * 64 + ns * 16 + l15;
        boffs[ns] = (r * 4 + (kg ^ ((r >> 1) & 3))) * 8;
    }

#define STAGE(OS, SA, SB, KK) do {                                           \
        __builtin_amdgcn_global_load_lds(                                    \
            (gu32*)(const void*)((SA) + (KK) * 32),                          \
            (lu32*)(void*)&Als[(OS) * ABUF + aBase], 16, 0, 0);              \
        _Pragma("unroll")                                                    \
        for (int q_ = 0; q_ < 2; ++q_)                                       \
            __builtin_amdgcn_global_load_lds(                                \
                (gu32*)(const void*)(tbt + (SB) + bRC[q_] + (KK) * 32),      \
                (lu32*)(void*)&Bls[(OS) * BBUF + bBase[q_]], 16, 0, 0);      \
    } while (0)

    int curT = blockIdx.x;
    const unsigned short* sA = w1b + (size_t)(curT >> 2) * 65536 + aRC;
    size_t sB = (size_t)(curT & 3) * 131072;
    int oc = 0, on = 1, os = 2;
    STAGE(0, sA, sB, 0);
    STAGE(1, sA, sB, 1);

    f32x4 acc[4][4] = {};
    bool avail = false;
    int ntReg = NTILES;

    for (;;) {
        const int m0 = (curT >> 2) * 128;
        const int n0 = (curT & 3) * 256;

        #pragma unroll
        for (int kt = 0; kt < NKT; ++kt) {
            // counted vmcnt: newest stage (3 loads) stays in flight across
            // the barrier; only on the provably-final iteration drain fully.
            if (kt == NKT - 1 && !avail)
                asm volatile("s_waitcnt vmcnt(0)" ::: "memory");
            else
                asm volatile("s_waitcnt vmcnt(3)" ::: "memory");
            __builtin_amdgcn_s_barrier();
            __builtin_amdgcn_sched_barrier(0);

            if (kt < 14) {
                STAGE(os, sA, sB, kt + 2);
            } else if (kt == 14) {
                ntReg = sNxt;                  // written at kt==10, 4 barriers ago
                avail = (ntReg < NTILES);
                if (avail) {
                    sA = w1b + (size_t)(ntReg >> 2) * 65536 + aRC;
                    sB = (size_t)(ntReg & 3) * 131072;
                    STAGE(os, sA, sB, 0);
                }
            } else {
                if (avail) STAGE(os, sA, sB, 1);
            }

            if (kt == 10 && tid == 0)
                sNxt = GRID + atomicAdd(ctr, 1);

            const unsigned short* ab = &Als[oc * ABUF];
            const unsigned short* bb = &Bls[oc * BBUF];
            bf16x8 af[4], bfr[4];
            #pragma unroll
            for (int ms = 0; ms < 4; ++ms)
                af[ms] = *reinterpret_cast<const bf16x8*>(&ab[aoffs[ms]]);
            #pragma unroll
            for (int ns = 0; ns < 4; ++ns)
                bfr[ns] = *reinterpret_cast<const bf16x8*>(&bb[boffs[ns]]);
            __builtin_amdgcn_s_setprio(1);
            #pragma unroll
            for (int ms = 0; ms < 4; ++ms)
                #pragma unroll
                for (int ns = 0; ns < 4; ++ns)
                    acc[ms][ns] = __builtin_amdgcn_mfma_f32_16x16x32_bf16(
                        af[ms], bfr[ns], acc[ms][ns], 0, 0, 0);
            __builtin_amdgcn_s_setprio(0);

            const int t_ = oc; oc = on; on = os; os = t_;   // rotate buffers
        }

        // ---- epilogue (overlaps next tile's first STAGEs, already issued) --
        {
            const int h0 = m0 / 513;
            const int mb = (h0 + 1) * 513;
            const bool cross = (mb < m0 + 128);

            float wcv[4][4];
            #pragma unroll
            for (int ms = 0; ms < 4; ++ms)
                #pragma unroll
                for (int v = 0; v < 4; ++v)
                    wcv[ms][v] =
                        w1[(size_t)(m0 + wr * 64 + ms * 16 + kg * 4 + v) * 513 + 512];

            #pragma unroll
            for (int ns = 0; ns < 4; ++ns) {
                const int ncol = n0 + wc * 64 + ns * 16 + l15;
                const float tv = tc[ncol];
                const float* xrow = xh + (size_t)ncol * 513;
                float s0 = 0.f, s1 = 0.f;
                #pragma unroll
                for (int ms = 0; ms < 4; ++ms) {
                    const int mbase = m0 + wr * 64 + ms * 16 + kg * 4;
                    f32x4 c = acc[ms][ns];
                    c[0] += wcv[ms][0] * tv; c[1] += wcv[ms][1] * tv;
                    c[2] += wcv[ms][2] * tv; c[3] += wcv[ms][3] * tv;
                    if (mbase + 3 < mb) {
                        const f32x4a xv =
                            *reinterpret_cast<const f32x4a*>(xrow + (mbase - h0 * 513));
                        s0 += c[0]*xv[0] + c[1]*xv[1] + c[2]*xv[2] + c[3]*xv[3];
                    } else if (mbase >= mb) {
                        const f32x4a xv =
                            *reinterpret_cast<const f32x4a*>(xrow + (mbase - mb));
                        s1 += c[0]*xv[0] + c[1]*xv[1] + c[2]*xv[2] + c[3]*xv[3];
                    } else {
                        #pragma unroll
                        for (int v = 0; v < 4; ++v) {
                            const int m = mbase + v;
                            const bool lo = (m < mb);
                            const int i = lo ? (m - h0 * 513) : (m - mb);
                            const float val = c[v] * xrow[i];
                            if (lo) s0 += val; else s1 += val;
                        }
                    }
                }
                s0 += __shfl_xor(s0, 16); s0 += __shfl_xor(s0, 32);
                if (lane < 16) atomicAdd(&y1acc[(size_t)ncol * HID + h0], s0);
                if (cross) {
                    s1 += __shfl_xor(s1, 16); s1 += __shfl_xor(s1, 32);
                    if (lane < 16 && (h0 + 1) < HID)
                        atomicAdd(&y1acc[(size_t)ncol * HID + h0 + 1], s1);
                }
            }
            #pragma unroll
            for (int ms = 0; ms < 4; ++ms)
                #pragma unroll
                for (int ns = 0; ns < 4; ++ns)
                    acc[ms][ns] = (f32x4){0.f, 0.f, 0.f, 0.f};
        }

        if (!avail) break;
        curT = ntReg;
    }
#undef STAGE
}

// ---------------- fallback GEMM (fp32-A path, no prep2 needed) --------------
__global__ __launch_bounds__(512, 4) void gemm_fused_fb(
    const float* __restrict__ w1, const unsigned short* __restrict__ tbt,
    const float* __restrict__ xh, const float* __restrict__ tc,
    float* __restrict__ y1acc)
{
    __shared__ float          Afs[2][64 * BK];
    __shared__ unsigned short Bls[2][512 * BK];

    const int bm = blockIdx.x >> 1;
    const int bn = blockIdx.x & 1;
    const int m0 = bm * 64;
    const int n0 = bn * 512;
    const int tid  = threadIdx.x;
    const int wv   = tid >> 6;
    const int lane = tid & 63;
    const int l15  = lane & 15;
    const int kg   = lane >> 4;

    const int ar  = tid >> 3;
    const int acl = (tid & 7) ^ (ar & 7);
    const float* asrc = w1 + (size_t)(m0 + ar) * 513 + acl * 4;
    const int aBase = (wv * 64) * 4;

    const unsigned short* bsrc[4];
    int bBase[4];
    #pragma unroll
    for (int q = 0; q < 4; ++q) {
        const int p  = q * 512 + tid;
        const int r  = p >> 2;
        const int cl = (p & 3) ^ ((r >> 1) & 3);
        bsrc[q] = tbt + (size_t)(n0 + r) * 512 + cl * 8;
        bBase[q] = (q * 512 + wv * 64) * 8;
    }

    int aoff0[4], aoff1[4], boffs[4];
    #pragma unroll
    for (int ms = 0; ms < 4; ++ms) {
        const int r = ms * 16 + l15;
        aoff0[ms] = r * 32 + (((kg * 2) + 0) ^ (r & 7)) * 4;
        aoff1[ms] = r * 32 + (((kg * 2) + 1) ^ (r & 7)) * 4;
    }
    #pragma unroll
    for (int ns = 0; ns < 4; ++ns) {
        const int r = wv * 64 + ns * 16 + l15;
        boffs[ns] = ((r << 2) | (kg ^ ((r >> 1) & 3))) * 8;
    }

    f32x4 acc[4][4] = {};

#define STAGE_FB(BUF, KT) do {                                               \
        const int k32_ = (KT) * BK;                                          \
        _Pragma("unroll")                                                    \
        for (int q_ = 0; q_ < 4; ++q_)                                       \
            __builtin_amdgcn_global_load_lds(                                \
                (gu32*)(const void*)(bsrc[q_] + k32_),                       \
                (lu32*)(void*)&Bls[BUF][bBase[q_]], 16, 0, 0);               \
        __builtin_amdgcn_global_load_lds(                                    \
            (gu32*)(const void*)(asrc + k32_),                               \
            (lu32*)(void*)&Afs[BUF][aBase], 16, 0, 0);                       \
    } while (0)

    STAGE_FB(0, 0);
    __syncthreads();

    for (int kt = 0; kt < NKT; ++kt) {
        const int cur = kt & 1;
        if (kt + 1 < NKT) STAGE_FB(cur ^ 1, kt + 1);

        const float*          ab = &Afs[cur][0];
        const unsigned short* bb = &Bls[cur][0];
        bf16x8 bfr[4];
        #pragma unroll
        for (int ns = 0; ns < 4; ++ns)
            bfr[ns] = *reinterpret_cast<const bf16x8*>(&bb[boffs[ns]]);
        #pragma unroll
        for (int ms = 0; ms < 4; ++ms) {
            const f32x4 lo = *reinterpret_cast<const f32x4*>(&ab[aoff0[ms]]);
            const f32x4 hi = *reinterpret_cast<const f32x4*>(&ab[aoff1[ms]]);
            u16x8 u;
            u[0] = f2bf(lo[0]); u[1] = f2bf(lo[1]);
            u[2] = f2bf(lo[2]); u[3] = f2bf(lo[3]);
            u[4] = f2bf(hi[0]); u[5] = f2bf(hi[1]);
            u[6] = f2bf(hi[2]); u[7] = f2bf(hi[3]);
            const bf16x8 af = __builtin_bit_cast(bf16x8, u);
            #pragma unroll
            for (int ns = 0; ns < 4; ++ns)
                acc[ms][ns] = __builtin_amdgcn_mfma_f32_16x16x32_bf16(
                    af, bfr[ns], acc[ms][ns], 0, 0, 0);
        }
        __syncthreads();
    }
#undef STAGE_FB

    const int h0 = m0 / 513;
    const int mb = (h0 + 1) * 513;
    const bool cross = (mb < m0 + 64);

    float wcv[4][4];
    #pragma unroll
    for (int ms = 0; ms < 4; ++ms)
        #pragma unroll
        for (int v = 0; v < 4; ++v)
            wcv[ms][v] = w1[(size_t)(m0 + ms * 16 + kg * 4 + v) * 513 + 512];

    #pragma unroll
    for (int ns = 0; ns < 4; ++ns) {
        const int ncol = n0 + wv * 64 + ns * 16 + l15;
        const float tv = tc[ncol];
        const float* xrow = xh + (size_t)ncol * 513;
        float s0 = 0.f, s1 = 0.f;
        #pragma unroll
        for (int ms = 0; ms < 4; ++ms) {
            #pragma unroll
            for (int v = 0; v < 4; ++v) {
                const int m = m0 + ms * 16 + kg * 4 + v;
                const bool lo = (m < mb);
                const int i = lo ? (m - h0 * 513) : (m - mb);
                const float val = (acc[ms][ns][v] + wcv[ms][v] * tv) * xrow[i];
                if (lo) s0 += val; else s1 += val;
            }
        }
        s0 += __shfl_xor(s0, 16); s0 += __shfl_xor(s0, 32);
        if (lane < 16) atomicAdd(&y1acc[(size_t)ncol * HID + h0], s0);
        if (cross) {
            s1 += __shfl_xor(s1, 16); s1 += __shfl_xor(s1, 32);
            if (lane < 16 && (h0 + 1) < HID)
                atomicAdd(&y1acc[(size_t)ncol * HID + h0 + 1], s1);
        }
    }
}

// ---------------- MLP tail ----------------
__global__ __launch_bounds__(128) void mlp_kernel(
    const float* __restrict__ y1acc, const float* __restrict__ b1,
    const float* __restrict__ W2, const float* __restrict__ b2,
    const float* __restrict__ W3, const float* __restrict__ b3,
    float* __restrict__ out)
{
    __shared__ float y1r[HID];
    __shared__ float y2r[HID];
    const int b = blockIdx.x;
    const int h = threadIdx.x;
    y1r[h] = y1acc[(size_t)b * HID + h] + b1[h];
    __syncthreads();
    float a = b2[h];
    const float* w2r = W2 + (size_t)h * HID;
    #pragma unroll 8
    for (int k = 0; k < HID; ++k) a += w2r[k] * y1r[k];
    y2r[h] = tanhf(a);
    __syncthreads();
    if (h < OUT_SZ) {
        float a3 = b3[h];
        const float* w3r = W3 + (size_t)h * HID;
        #pragma unroll 8
        for (int k = 0; k < HID; ++k) a3 += w3r[k] * y2r[k];
        out[(size_t)b * OUT_SZ + h] = fmaxf(a3, 0.f);
    }
}

extern "C" void kernel_launch(void* const* d_in, const int* in_sizes, int n_in,
                              void* d_out, int out_size, void* d_ws, size_t ws_size,
                              hipStream_t stream) {
    const float* img = (const float*)d_in[0];
    const float* tab = (const float*)d_in[1];
    const float* W1  = (const float*)d_in[2];
    const float* b1  = (const float*)d_in[3];
    const float* W2  = (const float*)d_in[4];
    const float* b2  = (const float*)d_in[5];
    const float* W3  = (const float*)d_in[6];
    const float* b3  = (const float*)d_in[7];
    float* out = (float*)d_out;

    char* ws = (char*)d_ws;
    float*          y1acc = (float*)ws;                        // 524288 B
    unsigned short* tbt   = (unsigned short*)(ws + 524288);    // 1048576 B
    float*          xh    = (float*)(ws + 1572864);            // 2101248 B (1024x513 f32)
    float*          tc    = (float*)(ws + 3674112);            // 4096 B
    int*            ctr   = (int*)(ws + 3678208);              // 16 B
    unsigned short* w1b   = (unsigned short*)(ws + 3678224);   // 67239936 B
    const size_t need = 3678224ULL + 67239936ULL;

    hipMemsetAsync(y1acc, 0, (size_t)B_SZ * HID * sizeof(float), stream);
    hipMemsetAsync(ctr, 0, 16, stream);
    prep_kernel<<<dim3(1024), dim3(256), 0, stream>>>(img, tab, tbt, xh, tc);
    if (ws_size >= need) {
        prep2_kernel<<<dim3(65664 * 64 / 256), dim3(256), 0, stream>>>(W1, w1b);
        gemm_fused<<<dim3(GRID), dim3(512), 0, stream>>>(W1, w1b, tbt, xh, tc, y1acc, ctr);
    } else {
        gemm_fused_fb<<<dim3(2052), dim3(512), 0, stream>>>(W1, tbt, xh, tc, y1acc);
    }
    mlp_kernel<<<dim3(1024), dim3(128), 0, stream>>>(y1acc, b1, W2, b2, W3, b3, out);
}

// Round 8
// 222.119 us; speedup vs baseline: 1.0777x; 1.0777x over previous
//
#include <hip/hip_runtime.h>
#include <hip/hip_bf16.h>

typedef __bf16 bf16x8 __attribute__((ext_vector_type(8)));
typedef float f32x4 __attribute__((ext_vector_type(4)));
typedef float f32x4u __attribute__((ext_vector_type(4), aligned(4)));
typedef unsigned short u16x8 __attribute__((ext_vector_type(8)));

typedef __attribute__((address_space(1))) const unsigned int gu32;
typedef __attribute__((address_space(3))) unsigned int lu32;

#define B_SZ   1024
#define IN_SZ  512
#define HID    128
#define OUT_SZ 64
#define BK     32        // (fallback kernel only)
#define NKT    16        // (fallback kernel only)
#define M_REAL 65664     // 128*513
#define M_PAD  65792     // 257*256

static __device__ __forceinline__ unsigned short f2bf(float f) {
    __hip_bfloat16 h = __float2bfloat16(f);
    return *reinterpret_cast<unsigned short*>(&h);
}

// ---------------- prep: t_hat bf16 [1024][512], tc, xhT [513][1024] --------
__global__ __launch_bounds__(256) void prep_kernel(
    const float* __restrict__ img, const float* __restrict__ tab,
    unsigned short* __restrict__ tbt, float* __restrict__ xhT,
    float* __restrict__ tc)
{
    const int blk = blockIdx.x;   // 0..1023
    for (int j = threadIdx.x; j < 512; j += 256) {
        float v = (j == 0) ? 1.0f : tab[(size_t)blk * IN_SZ + (j - 1)];
        tbt[(size_t)blk * 512 + j] = f2bf(v);
    }
    if (threadIdx.x == 0) tc[blk] = tab[(size_t)blk * IN_SZ + 511];
    if (blk < 513) {
        for (int b = threadIdx.x; b < B_SZ; b += 256)
            xhT[(size_t)blk * B_SZ + b] =
                (blk == 0) ? 1.0f : img[(size_t)b * IN_SZ + (blk - 1)];
    }
}

// -------- prep2: W1 fp32 [65664][513] -> bf16 [65792][512] (pad zeroed) ----
__global__ __launch_bounds__(256) void prep2_kernel(
    const float* __restrict__ w1, unsigned short* __restrict__ w1b)
{
    const long long gid = (long long)blockIdx.x * 256 + threadIdx.x;
    const int r  = (int)(gid >> 6);
    const int c8 = ((int)gid & 63) << 3;
    u16x8 u;
    if (r < M_REAL) {
        const float* src = w1 + (size_t)r * 513 + c8;
        const f32x4u lo = *reinterpret_cast<const f32x4u*>(src);
        const f32x4u hi = *reinterpret_cast<const f32x4u*>(src + 4);
        u[0] = f2bf(lo[0]); u[1] = f2bf(lo[1]); u[2] = f2bf(lo[2]); u[3] = f2bf(lo[3]);
        u[4] = f2bf(hi[0]); u[5] = f2bf(hi[1]); u[6] = f2bf(hi[2]); u[7] = f2bf(hi[3]);
    } else {
        u = (u16x8){0,0,0,0,0,0,0,0};
    }
    *reinterpret_cast<u16x8*>(w1b + (size_t)r * 512 + c8) = u;
}

// ---------------- main fused GEMM: 256x256 tile, BK=64, 8-phase ------------
// 8 waves (2M x 4N), wave-tile 128x64. LDS halves are quadrant-partitioned:
// A-half h = rows {wr*128 + h*64 + j}, B-half h = cols {wc*64 + h*32 + j}.
// Half-tile T staged at phases 4T-6..4T-3, consumed at 4T..4T+3 -> vmcnt(4).
__global__ __launch_bounds__(512, 2) void gemm_fused(
    const float* __restrict__ w1, const unsigned short* __restrict__ w1b,
    const unsigned short* __restrict__ tbt,
    const float* __restrict__ xhT, const float* __restrict__ tc,
    float* __restrict__ y1acc)
{
    __shared__ unsigned short Als[2 * 2 * 8192];   // [dbuf][mhalf][128*64]
    __shared__ unsigned short Bls[2 * 2 * 8192];   // [dbuf][nhalf][128*64]

    // T1: bijective XCD swizzle (nwg=1028: q=128, r=4)
    int wgid;
    {
        const int orig = blockIdx.x;
        const int xcd = orig & 7;
        const int pos = orig >> 3;
        wgid = (xcd < 4 ? xcd * 129 : 4 * 129 + (xcd - 4) * 128) + pos;
    }
    const int bm = wgid >> 2;             // 0..256
    const int bn = wgid & 3;              // 0..3
    const int m0 = bm * 256;
    const int n0 = bn * 256;
    const int tid  = threadIdx.x;
    const int wv   = tid >> 6;
    const int wr   = wv >> 2;             // 0..1
    const int wc   = wv & 3;              // 0..3
    const int lane = tid & 63;
    const int l15  = lane & 15;
    const int kg   = lane >> 4;

    // ---- staging source pointers (pre-swizzled: phys chunk p -> logical) ---
    // A half-tile: 128 rows x 8 chunks; thread t stages phys chunks t, 512+t.
    const unsigned short* aS[2][2];   // [which chunk][half]
    int aD[2];
    const unsigned short* bS[2][2];
    int bD[2];
    #pragma unroll
    for (int cq = 0; cq < 2; ++cq) {
        const int p  = cq * 512 + tid;
        const int rr = p >> 3;
        const int lc = (p & 7) ^ (rr & 7);
        { // A: rr = wr_*64 + j ; global row = m0 + wr_*128 + H*64 + j
            const int wr_ = rr >> 6, j = rr & 63;
            aS[cq][0] = w1b + (size_t)(m0 + wr_ * 128 +      j) * 512 + lc * 8;
            aS[cq][1] = w1b + (size_t)(m0 + wr_ * 128 + 64 + j) * 512 + lc * 8;
        }
        { // B: rr = wc_*32 + j2 ; global col = n0 + wc_*64 + H*32 + j2
            const int wc_ = rr >> 5, j2 = rr & 31;
            bS[cq][0] = tbt + (size_t)(n0 + wc_ * 64 +      j2) * 512 + lc * 8;
            bS[cq][1] = tbt + (size_t)(n0 + wc_ * 64 + 32 + j2) * 512 + lc * 8;
        }
        aD[cq] = p * 8;
        bD[cq] = p * 8;
    }

    // ---- fragment read offsets (u16 units within an 8192-elem half) -------
    int aoff[4][2], boff[2][2];
    #pragma unroll
    for (int mf = 0; mf < 4; ++mf)
        #pragma unroll
        for (int ks = 0; ks < 2; ++ks) {
            const int rr = wr * 64 + mf * 16 + l15;
            aoff[mf][ks] = rr * 64 + ((ks * 4 + kg) ^ (rr & 7)) * 8;
        }
    #pragma unroll
    for (int fr = 0; fr < 2; ++fr)
        #pragma unroll
        for (int ks = 0; ks < 2; ++ks) {
            const int rr = wc * 32 + fr * 16 + l15;
            boff[fr][ks] = rr * 64 + ((ks * 4 + kg) ^ (rr & 7)) * 8;
        }

    f32x4 acc[8][4] = {};
    bf16x8 fA[4][2], fB[2][2][2];   // fB[nq][fr][ks]

#define GL(SRC, DST) __builtin_amdgcn_global_load_lds(                       \
        (gu32*)(const void*)(SRC), (lu32*)(void*)(DST), 16, 0, 0)
#define STA(T, H) do {                                                       \
        unsigned short* b_ = &Als[((((T) & 1) << 1) + (H)) * 8192];          \
        GL(aS[0][H] + (T) * 64, b_ + aD[0]);                                 \
        GL(aS[1][H] + (T) * 64, b_ + aD[1]);                                 \
    } while (0)
#define STB(T, H) do {                                                       \
        unsigned short* b_ = &Bls[((((T) & 1) << 1) + (H)) * 8192];          \
        GL(bS[0][H] + (T) * 64, b_ + bD[0]);                                 \
        GL(bS[1][H] + (T) * 64, b_ + bD[1]);                                 \
    } while (0)

    // prologue: Ah0(0) Bh0(0) Ah1(0) Bh1(0) Ah0(1) Bh0(1)  (12 loads)
    STA(0, 0); STB(0, 0); STA(0, 1); STB(0, 1); STA(1, 0); STB(1, 0);
    asm volatile("s_waitcnt vmcnt(4)" ::: "memory");
    __builtin_amdgcn_s_barrier();

    #pragma unroll
    for (int P = 0; P < 32; ++P) {
        const int kt = P >> 2, q = P & 3, d = kt & 1, mh = q >> 1, nq = q & 1;
        const unsigned short* Ab = &Als[((d << 1) + mh) * 8192];
        const unsigned short* Bb = &Bls[((d << 1) + nq) * 8192];

        if (q == 0) {
            #pragma unroll
            for (int mf = 0; mf < 4; ++mf)
                #pragma unroll
                for (int ks = 0; ks < 2; ++ks)
                    fA[mf][ks] = *reinterpret_cast<const bf16x8*>(&Ab[aoff[mf][ks]]);
            #pragma unroll
            for (int fr = 0; fr < 2; ++fr)
                #pragma unroll
                for (int ks = 0; ks < 2; ++ks)
                    fB[0][fr][ks] = *reinterpret_cast<const bf16x8*>(&Bb[boff[fr][ks]]);
            if (kt + 1 <= 7) STA(kt + 1, 1);
        } else if (q == 1) {
            #pragma unroll
            for (int fr = 0; fr < 2; ++fr)
                #pragma unroll
                for (int ks = 0; ks < 2; ++ks)
                    fB[1][fr][ks] = *reinterpret_cast<const bf16x8*>(&Bb[boff[fr][ks]]);
            if (kt + 1 <= 7) STB(kt + 1, 1);
        } else if (q == 2) {
            #pragma unroll
            for (int mf = 0; mf < 4; ++mf)
                #pragma unroll
                for (int ks = 0; ks < 2; ++ks)
                    fA[mf][ks] = *reinterpret_cast<const bf16x8*>(&Ab[aoff[mf][ks]]);
            if (kt + 2 <= 7) STA(kt + 2, 0);
        } else {
            if (kt + 2 <= 7) STB(kt + 2, 0);
        }

        __builtin_amdgcn_s_barrier();
        asm volatile("s_waitcnt lgkmcnt(0)" ::: "memory");
        __builtin_amdgcn_sched_barrier(0);
        __builtin_amdgcn_s_setprio(1);
        #pragma unroll
        for (int mf = 0; mf < 4; ++mf)
            #pragma unroll
            for (int fr = 0; fr < 2; ++fr)
                #pragma unroll
                for (int ks = 0; ks < 2; ++ks)
                    acc[mh * 4 + mf][nq * 2 + fr] =
                        __builtin_amdgcn_mfma_f32_16x16x32_bf16(
                            fA[mf][ks], fB[nq][fr][ks],
                            acc[mh * 4 + mf][nq * 2 + fr], 0, 0, 0);
        __builtin_amdgcn_s_setprio(0);
        if (q == 3) {
            if (kt >= 6) asm volatile("s_waitcnt vmcnt(0)" ::: "memory");
            else         asm volatile("s_waitcnt vmcnt(4)" ::: "memory");
        }
        __builtin_amdgcn_s_barrier();
    }
#undef STA
#undef STB
#undef GL

    // ---- epilogue: + j=512 rank-1 term (fp32), reduce over i, atomics -----
    const int h0 = m0 / 513;
    const int mb = (h0 + 1) * 513;
    const bool cross = (mb < m0 + 256);

    float wcv[8][4];
    #pragma unroll
    for (int am = 0; am < 8; ++am)
        #pragma unroll
        for (int v = 0; v < 4; ++v) {
            const int g = m0 + wr * 128 + am * 16 + kg * 4 + v;
            wcv[am][v] = (g < M_REAL) ? w1[(size_t)g * 513 + 512] : 0.f;
        }

    #pragma unroll
    for (int an = 0; an < 4; ++an) {
        const int ncol = n0 + wc * 64 + an * 16 + l15;
        const float tv = tc[ncol];
        float s0 = 0.f, s1 = 0.f;
        #pragma unroll
        for (int am = 0; am < 8; ++am) {
            #pragma unroll
            for (int v = 0; v < 4; ++v) {
                const int m = m0 + wr * 128 + am * 16 + kg * 4 + v;
                const bool lo = (m < mb);
                const int i = lo ? (m - h0 * 513) : (m - mb);
                const float val = (acc[am][an][v] + wcv[am][v] * tv)
                                  * xhT[(size_t)i * B_SZ + ncol];
                if (lo) s0 += val; else s1 += val;
            }
        }
        s0 += __shfl_xor(s0, 16); s0 += __shfl_xor(s0, 32);
        if (lane < 16) atomicAdd(&y1acc[(size_t)ncol * HID + h0], s0);
        if (cross) {
            s1 += __shfl_xor(s1, 16); s1 += __shfl_xor(s1, 32);
            if (lane < 16 && (h0 + 1) < HID)
                atomicAdd(&y1acc[(size_t)ncol * HID + h0 + 1], s1);
        }
    }
}

// ---------------- fallback GEMM (fp32-A path, no prep2 needed) --------------
__global__ __launch_bounds__(512, 4) void gemm_fused_fb(
    const float* __restrict__ w1, const unsigned short* __restrict__ tbt,
    const float* __restrict__ xhT, const float* __restrict__ tc,
    float* __restrict__ y1acc)
{
    __shared__ float          Afs[2][64 * BK];
    __shared__ unsigned short Bls[2][512 * BK];

    const int bm = blockIdx.x >> 1;
    const int bn = blockIdx.x & 1;
    const int m0 = bm * 64;
    const int n0 = bn * 512;
    const int tid  = threadIdx.x;
    const int wv   = tid >> 6;
    const int lane = tid & 63;
    const int l15  = lane & 15;
    const int kg   = lane >> 4;

    const int ar  = tid >> 3;
    const int acl = (tid & 7) ^ (ar & 7);
    const float* asrc = w1 + (size_t)(m0 + ar) * 513 + acl * 4;
    const int aBase = (wv * 64) * 4;

    const unsigned short* bsrc[4];
    int bBase[4];
    #pragma unroll
    for (int q = 0; q < 4; ++q) {
        const int p  = q * 512 + tid;
        const int r  = p >> 2;
        const int cl = (p & 3) ^ ((r >> 1) & 3);
        bsrc[q] = tbt + (size_t)(n0 + r) * 512 + cl * 8;
        bBase[q] = (q * 512 + wv * 64) * 8;
    }

    int aoff0[4], aoff1[4], boffs[4];
    #pragma unroll
    for (int ms = 0; ms < 4; ++ms) {
        const int r = ms * 16 + l15;
        aoff0[ms] = r * 32 + (((kg * 2) + 0) ^ (r & 7)) * 4;
        aoff1[ms] = r * 32 + (((kg * 2) + 1) ^ (r & 7)) * 4;
    }
    #pragma unroll
    for (int ns = 0; ns < 4; ++ns) {
        const int r = wv * 64 + ns * 16 + l15;
        boffs[ns] = ((r << 2) | (kg ^ ((r >> 1) & 3))) * 8;
    }

    f32x4 acc[4][4] = {};

#define STAGE_FB(BUF, KT) do {                                               \
        const int k32_ = (KT) * BK;                                          \
        _Pragma("unroll")                                                    \
        for (int q_ = 0; q_ < 4; ++q_)                                       \
            __builtin_amdgcn_global_load_lds(                                \
                (gu32*)(const void*)(bsrc[q_] + k32_),                       \
                (lu32*)(void*)&Bls[BUF][bBase[q_]], 16, 0, 0);               \
        __builtin_amdgcn_global_load_lds(                                    \
            (gu32*)(const void*)(asrc + k32_),                               \
            (lu32*)(void*)&Afs[BUF][aBase], 16, 0, 0);                       \
    } while (0)

    STAGE_FB(0, 0);
    __syncthreads();

    for (int kt = 0; kt < NKT; ++kt) {
        const int cur = kt & 1;
        if (kt + 1 < NKT) STAGE_FB(cur ^ 1, kt + 1);

        const float*          ab = &Afs[cur][0];
        const unsigned short* bb = &Bls[cur][0];
        bf16x8 bfr[4];
        #pragma unroll
        for (int ns = 0; ns < 4; ++ns)
            bfr[ns] = *reinterpret_cast<const bf16x8*>(&bb[boffs[ns]]);
        #pragma unroll
        for (int ms = 0; ms < 4; ++ms) {
            const f32x4 lo = *reinterpret_cast<const f32x4*>(&ab[aoff0[ms]]);
            const f32x4 hi = *reinterpret_cast<const f32x4*>(&ab[aoff1[ms]]);
            u16x8 u;
            u[0] = f2bf(lo[0]); u[1] = f2bf(lo[1]);
            u[2] = f2bf(lo[2]); u[3] = f2bf(lo[3]);
            u[4] = f2bf(hi[0]); u[5] = f2bf(hi[1]);
            u[6] = f2bf(hi[2]); u[7] = f2bf(hi[3]);
            const bf16x8 af = __builtin_bit_cast(bf16x8, u);
            #pragma unroll
            for (int ns = 0; ns < 4; ++ns)
                acc[ms][ns] = __builtin_amdgcn_mfma_f32_16x16x32_bf16(
                    af, bfr[ns], acc[ms][ns], 0, 0, 0);
        }
        __syncthreads();
    }
#undef STAGE_FB

    const int h0 = m0 / 513;
    const int mb = (h0 + 1) * 513;
    const bool cross = (mb < m0 + 64);

    float wcv[4][4];
    #pragma unroll
    for (int ms = 0; ms < 4; ++ms)
        #pragma unroll
        for (int v = 0; v < 4; ++v)
            wcv[ms][v] = w1[(size_t)(m0 + ms * 16 + kg * 4 + v) * 513 + 512];

    #pragma unroll
    for (int ns = 0; ns < 4; ++ns) {
        const int ncol = n0 + wv * 64 + ns * 16 + l15;
        const float tv = tc[ncol];
        float s0 = 0.f, s1 = 0.f;
        #pragma unroll
        for (int ms = 0; ms < 4; ++ms) {
            #pragma unroll
            for (int v = 0; v < 4; ++v) {
                const int m = m0 + ms * 16 + kg * 4 + v;
                const bool lo = (m < mb);
                const int i = lo ? (m - h0 * 513) : (m - mb);
                const float val = (acc[ms][ns][v] + wcv[ms][v] * tv)
                                  * xhT[(size_t)i * B_SZ + ncol];
                if (lo) s0 += val; else s1 += val;
            }
        }
        s0 += __shfl_xor(s0, 16); s0 += __shfl_xor(s0, 32);
        if (lane < 16) atomicAdd(&y1acc[(size_t)ncol * HID + h0], s0);
        if (cross) {
            s1 += __shfl_xor(s1, 16); s1 += __shfl_xor(s1, 32);
            if (lane < 16 && (h0 + 1) < HID)
                atomicAdd(&y1acc[(size_t)ncol * HID + h0 + 1], s1);
        }
    }
}

// ---------------- MLP tail ----------------
__global__ __launch_bounds__(128) void mlp_kernel(
    const float* __restrict__ y1acc, const float* __restrict__ b1,
    const float* __restrict__ W2, const float* __restrict__ b2,
    const float* __restrict__ W3, const float* __restrict__ b3,
    float* __restrict__ out)
{
    __shared__ float y1r[HID];
    __shared__ float y2r[HID];
    const int b = blockIdx.x;
    const int h = threadIdx.x;
    y1r[h] = y1acc[(size_t)b * HID + h] + b1[h];
    __syncthreads();
    float a = b2[h];
    const float* w2r = W2 + (size_t)h * HID;
    #pragma unroll 8
    for (int k = 0; k < HID; ++k) a += w2r[k] * y1r[k];
    y2r[h] = tanhf(a);
    __syncthreads();
    if (h < OUT_SZ) {
        float a3 = b3[h];
        const float* w3r = W3 + (size_t)h * HID;
        #pragma unroll 8
        for (int k = 0; k < HID; ++k) a3 += w3r[k] * y2r[k];
        out[(size_t)b * OUT_SZ + h] = fmaxf(a3, 0.f);
    }
}

extern "C" void kernel_launch(void* const* d_in, const int* in_sizes, int n_in,
                              void* d_out, int out_size, void* d_ws, size_t ws_size,
                              hipStream_t stream) {
    const float* img = (const float*)d_in[0];
    const float* tab = (const float*)d_in[1];
    const float* W1  = (const float*)d_in[2];
    const float* b1  = (const float*)d_in[3];
    const float* W2  = (const float*)d_in[4];
    const float* b2  = (const float*)d_in[5];
    const float* W3  = (const float*)d_in[6];
    const float* b3  = (const float*)d_in[7];
    float* out = (float*)d_out;

    char* ws = (char*)d_ws;
    float*          y1acc = (float*)ws;                        // 524288 B
    unsigned short* tbt   = (unsigned short*)(ws + 524288);    // 1048576 B
    float*          xhT   = (float*)(ws + 1572864);            // 2101248 B (513x1024)
    float*          tc    = (float*)(ws + 3674112);            // 4096 B
    unsigned short* w1b   = (unsigned short*)(ws + 3678208);   // 65792*512*2 = 67371008 B
    const size_t need = 3678208ULL + 67371008ULL;

    hipMemsetAsync(y1acc, 0, (size_t)B_SZ * HID * sizeof(float), stream);
    prep_kernel<<<dim3(1024), dim3(256), 0, stream>>>(img, tab, tbt, xhT, tc);
    if (ws_size >= need) {
        prep2_kernel<<<dim3(M_PAD * 64 / 256), dim3(256), 0, stream>>>(W1, w1b);
        gemm_fused<<<dim3(1028), dim3(512), 0, stream>>>(W1, w1b, tbt, xhT, tc, y1acc);
    } else {
        gemm_fused_fb<<<dim3(2052), dim3(512), 0, stream>>>(W1, tbt, xhT, tc, y1acc);
    }
    mlp_kernel<<<dim3(1024), dim3(128), 0, stream>>>(y1acc, b1, W2, b2, W3, b3, out);
}

// Round 9
// 216.158 us; speedup vs baseline: 1.1074x; 1.0276x over previous
//
#include <hip/hip_runtime.h>
#include <hip/hip_bf16.h>

typedef __bf16 bf16x8 __attribute__((ext_vector_type(8)));
typedef float f32x4 __attribute__((ext_vector_type(4)));
typedef float f32x4u __attribute__((ext_vector_type(4), aligned(4)));
typedef unsigned short u16x8 __attribute__((ext_vector_type(8)));

typedef __attribute__((address_space(1))) const unsigned int gu32;
typedef __attribute__((address_space(3))) unsigned int lu32;

#define B_SZ   1024
#define IN_SZ  512
#define HID    128
#define OUT_SZ 64
#define BK     32
#define NKT    16        // K main loop = 512
#define M2     65536     // 128 h x 512 i   (main GEMM M, power of 2)

static __device__ __forceinline__ unsigned short f2bf(float f) {
    __hip_bfloat16 h = __float2bfloat16(f);
    return *reinterpret_cast<unsigned short*>(&h);
}

// ---------------- prep: t_hat bf16 [1024][512], tc, xhT [513][1024] --------
__global__ __launch_bounds__(256) void prep_kernel(
    const float* __restrict__ img, const float* __restrict__ tab,
    unsigned short* __restrict__ tbt, float* __restrict__ xhT,
    float* __restrict__ tc)
{
    const int blk = blockIdx.x;   // 0..1023
    for (int j = threadIdx.x; j < 512; j += 256) {
        float v = (j == 0) ? 1.0f : tab[(size_t)blk * IN_SZ + (j - 1)];
        tbt[(size_t)blk * 512 + j] = f2bf(v);
    }
    if (threadIdx.x == 0) tc[blk] = tab[(size_t)blk * IN_SZ + 511];
    if (blk < 513) {
        for (int b = threadIdx.x; b < B_SZ; b += 256)
            xhT[(size_t)blk * B_SZ + b] =
                (blk == 0) ? 1.0f : img[(size_t)b * IN_SZ + (blk - 1)];
    }
}

// -------- prep2: W1 -> w1c bf16 [65536][512]; row r=(h<<9)+i <- W1[h*513+i] -
__global__ __launch_bounds__(256) void prep2_kernel(
    const float* __restrict__ w1, unsigned short* __restrict__ w1c)
{
    const long long gid = (long long)blockIdx.x * 256 + threadIdx.x;
    const int r  = (int)(gid >> 6);                 // 0..65535
    const int c8 = ((int)gid & 63) << 3;
    const size_t srow = (size_t)(r >> 9) * 513 + (r & 511);
    const float* src = w1 + srow * 513 + c8;
    const f32x4u lo = *reinterpret_cast<const f32x4u*>(src);
    const f32x4u hi = *reinterpret_cast<const f32x4u*>(src + 4);
    u16x8 u;
    u[0] = f2bf(lo[0]); u[1] = f2bf(lo[1]); u[2] = f2bf(lo[2]); u[3] = f2bf(lo[3]);
    u[4] = f2bf(hi[0]); u[5] = f2bf(hi[1]); u[6] = f2bf(hi[2]); u[7] = f2bf(hi[3]);
    *reinterpret_cast<u16x8*>(w1c + (size_t)r * 512 + c8) = u;
}

// -------- prep3: wrowT[j][h] = W1[(h*513+512)*513 + j]  (513 x 128 f32) ----
__global__ __launch_bounds__(256) void prep3_kernel(
    const float* __restrict__ w1, float* __restrict__ wrowT)
{
    const int idx = blockIdx.x * 256 + threadIdx.x;
    if (idx < 513 * 128) {
        const int j = idx >> 7, h = idx & 127;
        wrowT[idx] = w1[((size_t)h * 513 + 512) * 513 + j];
    }
}

// ---------------- main fused GEMM (R5 structure, power-of-2 geometry) ------
// BM=128, BN=256, BK=32. 8 waves (2M x 4N), wave-tile 64x64.
// 3-buf LDS, counted vmcnt(3), XCD swizzle; grid 2048 = exactly 4 gens.
__global__ __launch_bounds__(512, 4) void gemm_fused(
    const float* __restrict__ w1, const unsigned short* __restrict__ w1c,
    const unsigned short* __restrict__ tbt,
    const float* __restrict__ xhT, const float* __restrict__ tc,
    float* __restrict__ y1acc)
{
    __shared__ unsigned short Als[3][128 * BK];   // 3 x 8 KB
    __shared__ unsigned short Bls[3][256 * BK];   // 3 x 16 KB

    // T1: XCD swizzle, nwg=2048 (%8==0 -> simple bijective chunking)
    const int wgid = (blockIdx.x & 7) * 256 + (blockIdx.x >> 3);
    const int bm = wgid >> 2;             // 0..511
    const int bn = wgid & 3;              // 0..3
    const int m0 = bm * 128;              // in m2-space
    const int n0 = bn * 256;
    const int tid  = threadIdx.x;
    const int wv   = tid >> 6;
    const int wr   = wv >> 2;             // 0..1
    const int wc   = wv & 3;              // 0..3
    const int lane = tid & 63;
    const int l15  = lane & 15;
    const int kg   = lane >> 4;

    // A staging: phys chunk p = tid (128 rows x 4 chunks), source pre-swizzled
    const unsigned short* asrc;
    {
        const int r  = tid >> 2;
        const int cl = (tid & 3) ^ ((r >> 1) & 3);
        asrc = w1c + (size_t)(m0 + r) * 512 + cl * 8;
    }
    const int aBase = (wv * 64) * 8;

    // B staging: phys chunks p = tid, 512+tid (256 rows x 4 chunks)
    const unsigned short* bsrc[2];
    int bBase[2];
    #pragma unroll
    for (int q = 0; q < 2; ++q) {
        const int p  = q * 512 + tid;
        const int r  = p >> 2;
        const int cl = (p & 3) ^ ((r >> 1) & 3);
        bsrc[q] = tbt + (size_t)(n0 + r) * 512 + cl * 8;
        bBase[q] = (q * 512 + wv * 64) * 8;
    }

    // fragment read offsets (u16 units); phys chunk = kg ^ ((r>>1)&3)
    int aoffs[4], boffs[4];
    #pragma unroll
    for (int ms = 0; ms < 4; ++ms) {
        const int r = wr * 64 + ms * 16 + l15;
        aoffs[ms] = (r * 4 + (kg ^ ((r >> 1) & 3))) * 8;
    }
    #pragma unroll
    for (int ns = 0; ns < 4; ++ns) {
        const int r = wc * 64 + ns * 16 + l15;
        boffs[ns] = (r * 4 + (kg ^ ((r >> 1) & 3))) * 8;
    }

    f32x4 acc[4][4] = {};

#define STAGE(BUF, KT) do {                                                  \
        const int k32_ = (KT) * BK;                                          \
        __builtin_amdgcn_global_load_lds(                                    \
            (gu32*)(const void*)(asrc + k32_),                               \
            (lu32*)(void*)&Als[BUF][aBase], 16, 0, 0);                       \
        _Pragma("unroll")                                                    \
        for (int q_ = 0; q_ < 2; ++q_)                                       \
            __builtin_amdgcn_global_load_lds(                                \
                (gu32*)(const void*)(bsrc[q_] + k32_),                       \
                (lu32*)(void*)&Bls[BUF][bBase[q_]], 16, 0, 0);               \
    } while (0)

    STAGE(0, 0);
    STAGE(1, 1);

    #pragma unroll
    for (int kt = 0; kt < NKT; ++kt) {
        if (kt == NKT - 1) asm volatile("s_waitcnt vmcnt(0)" ::: "memory");
        else               asm volatile("s_waitcnt vmcnt(3)" ::: "memory");
        __builtin_amdgcn_s_barrier();
        __builtin_amdgcn_sched_barrier(0);

        if (kt + 2 < NKT) STAGE((kt + 2) % 3, kt + 2);

        const int cur = kt % 3;
        const unsigned short* ab = &Als[cur][0];
        const unsigned short* bb = &Bls[cur][0];
        bf16x8 af[4], bfr[4];
        #pragma unroll
        for (int ms = 0; ms < 4; ++ms)
            af[ms] = *reinterpret_cast<const bf16x8*>(&ab[aoffs[ms]]);
        #pragma unroll
        for (int ns = 0; ns < 4; ++ns)
            bfr[ns] = *reinterpret_cast<const bf16x8*>(&bb[boffs[ns]]);
        __builtin_amdgcn_s_setprio(1);
        #pragma unroll
        for (int ms = 0; ms < 4; ++ms)
            #pragma unroll
            for (int ns = 0; ns < 4; ++ns)
                acc[ms][ns] = __builtin_amdgcn_mfma_f32_16x16x32_bf16(
                    af[ms], bfr[ns], acc[ms][ns], 0, 0, 0);
        __builtin_amdgcn_s_setprio(0);
    }
#undef STAGE

    // ---- epilogue: + j=512 rank-1 term (fp32), reduce over i, one atomic --
    const int h0    = bm >> 2;            // 128 | 512 -> block within one h
    const int ibase = (bm & 3) * 128;
    const size_t orow = (size_t)h0 * 513; // W1 row base for this h

    float wcv[4][4];
    #pragma unroll
    for (int ms = 0; ms < 4; ++ms)
        #pragma unroll
        for (int v = 0; v < 4; ++v) {
            const int i_ = ibase + wr * 64 + ms * 16 + kg * 4 + v;
            wcv[ms][v] = w1[(orow + i_) * 513 + 512];
        }

    #pragma unroll
    for (int ns = 0; ns < 4; ++ns) {
        const int ncol = n0 + wc * 64 + ns * 16 + l15;
        const float tv = tc[ncol];
        float s0 = 0.f;
        #pragma unroll
        for (int ms = 0; ms < 4; ++ms) {
            const int i_ = ibase + wr * 64 + ms * 16 + kg * 4;
            #pragma unroll
            for (int v = 0; v < 4; ++v)
                s0 += (acc[ms][ns][v] + wcv[ms][v] * tv)
                      * xhT[(size_t)(i_ + v) * B_SZ + ncol];
        }
        s0 += __shfl_xor(s0, 16); s0 += __shfl_xor(s0, 32);
        if (lane < 16) atomicAdd(&y1acc[(size_t)ncol * HID + h0], s0);
    }
}

// -------- tail: y1acc[n,h] += x_hat[n,512] * sum_{j<=512} wrowT[j][h]*t_hat --
__global__ __launch_bounds__(128) void tail_kernel(
    const float* __restrict__ img, const float* __restrict__ tab,
    const float* __restrict__ wrowT, float* __restrict__ y1acc)
{
    __shared__ float tls[4][513];
    const int b0 = blockIdx.x * 4;
    const int h  = threadIdx.x;
    #pragma unroll
    for (int q = 0; q < 4; ++q)
        for (int j = h; j < 513; j += 128)
            tls[q][j] = (j == 0) ? 1.0f : tab[(size_t)(b0 + q) * IN_SZ + (j - 1)];
    __syncthreads();
    float a0 = 0.f, a1 = 0.f, a2 = 0.f, a3 = 0.f;
    #pragma unroll 8
    for (int j = 0; j < 513; ++j) {
        const float w = wrowT[j * 128 + h];
        a0 += w * tls[0][j]; a1 += w * tls[1][j];
        a2 += w * tls[2][j]; a3 += w * tls[3][j];
    }
    atomicAdd(&y1acc[(size_t)(b0 + 0) * HID + h], a0 * img[(size_t)(b0 + 0) * IN_SZ + 511]);
    atomicAdd(&y1acc[(size_t)(b0 + 1) * HID + h], a1 * img[(size_t)(b0 + 1) * IN_SZ + 511]);
    atomicAdd(&y1acc[(size_t)(b0 + 2) * HID + h], a2 * img[(size_t)(b0 + 2) * IN_SZ + 511]);
    atomicAdd(&y1acc[(size_t)(b0 + 3) * HID + h], a3 * img[(size_t)(b0 + 3) * IN_SZ + 511]);
}

// ---------------- fallback GEMM (fp32-A path, no prep2 needed) --------------
__global__ __launch_bounds__(512, 4) void gemm_fused_fb(
    const float* __restrict__ w1, const unsigned short* __restrict__ tbt,
    const float* __restrict__ xhT, const float* __restrict__ tc,
    float* __restrict__ y1acc)
{
    __shared__ float          Afs[2][64 * BK];
    __shared__ unsigned short Bls[2][512 * BK];

    const int bm = blockIdx.x >> 1;
    const int bn = blockIdx.x & 1;
    const int m0 = bm * 64;
    const int n0 = bn * 512;
    const int tid  = threadIdx.x;
    const int wv   = tid >> 6;
    const int lane = tid & 63;
    const int l15  = lane & 15;
    const int kg   = lane >> 4;

    const int ar  = tid >> 3;
    const int acl = (tid & 7) ^ (ar & 7);
    const float* asrc = w1 + (size_t)(m0 + ar) * 513 + acl * 4;
    const int aBase = (wv * 64) * 4;

    const unsigned short* bsrc[4];
    int bBase[4];
    #pragma unroll
    for (int q = 0; q < 4; ++q) {
        const int p  = q * 512 + tid;
        const int r  = p >> 2;
        const int cl = (p & 3) ^ ((r >> 1) & 3);
        bsrc[q] = tbt + (size_t)(n0 + r) * 512 + cl * 8;
        bBase[q] = (q * 512 + wv * 64) * 8;
    }

    int aoff0[4], aoff1[4], boffs[4];
    #pragma unroll
    for (int ms = 0; ms < 4; ++ms) {
        const int r = ms * 16 + l15;
        aoff0[ms] = r * 32 + (((kg * 2) + 0) ^ (r & 7)) * 4;
        aoff1[ms] = r * 32 + (((kg * 2) + 1) ^ (r & 7)) * 4;
    }
    #pragma unroll
    for (int ns = 0; ns < 4; ++ns) {
        const int r = wv * 64 + ns * 16 + l15;
        boffs[ns] = ((r << 2) | (kg ^ ((r >> 1) & 3))) * 8;
    }

    f32x4 acc[4][4] = {};

#define STAGE_FB(BUF, KT) do {                                               \
        const int k32_ = (KT) * BK;                                          \
        _Pragma("unroll")                                                    \
        for (int q_ = 0; q_ < 4; ++q_)                                       \
            __builtin_amdgcn_global_load_lds(                                \
                (gu32*)(const void*)(bsrc[q_] + k32_),                       \
                (lu32*)(void*)&Bls[BUF][bBase[q_]], 16, 0, 0);               \
        __builtin_amdgcn_global_load_lds(                                    \
            (gu32*)(const void*)(asrc + k32_),                               \
            (lu32*)(void*)&Afs[BUF][aBase], 16, 0, 0);                       \
    } while (0)

    STAGE_FB(0, 0);
    __syncthreads();

    for (int kt = 0; kt < NKT; ++kt) {
        const int cur = kt & 1;
        if (kt + 1 < NKT) STAGE_FB(cur ^ 1, kt + 1);

        const float*          ab = &Afs[cur][0];
        const unsigned short* bb = &Bls[cur][0];
        bf16x8 bfr[4];
        #pragma unroll
        for (int ns = 0; ns < 4; ++ns)
            bfr[ns] = *reinterpret_cast<const bf16x8*>(&bb[boffs[ns]]);
        #pragma unroll
        for (int ms = 0; ms < 4; ++ms) {
            const f32x4 lo = *reinterpret_cast<const f32x4*>(&ab[aoff0[ms]]);
            const f32x4 hi = *reinterpret_cast<const f32x4*>(&ab[aoff1[ms]]);
            u16x8 u;
            u[0] = f2bf(lo[0]); u[1] = f2bf(lo[1]);
            u[2] = f2bf(lo[2]); u[3] = f2bf(lo[3]);
            u[4] = f2bf(hi[0]); u[5] = f2bf(hi[1]);
            u[6] = f2bf(hi[2]); u[7] = f2bf(hi[3]);
            const bf16x8 af = __builtin_bit_cast(bf16x8, u);
            #pragma unroll
            for (int ns = 0; ns < 4; ++ns)
                acc[ms][ns] = __builtin_amdgcn_mfma_f32_16x16x32_bf16(
                    af, bfr[ns], acc[ms][ns], 0, 0, 0);
        }
        __syncthreads();
    }
#undef STAGE_FB

    const int h0 = m0 / 513;
    const int mb = (h0 + 1) * 513;
    const bool cross = (mb < m0 + 64);

    float wcv[4][4];
    #pragma unroll
    for (int ms = 0; ms < 4; ++ms)
        #pragma unroll
        for (int v = 0; v < 4; ++v)
            wcv[ms][v] = w1[(size_t)(m0 + ms * 16 + kg * 4 + v) * 513 + 512];

    #pragma unroll
    for (int ns = 0; ns < 4; ++ns) {
        const int ncol = n0 + wv * 64 + ns * 16 + l15;
        const float tv = tc[ncol];
        float s0 = 0.f, s1 = 0.f;
        #pragma unroll
        for (int ms = 0; ms < 4; ++ms) {
            #pragma unroll
            for (int v = 0; v < 4; ++v) {
                const int m = m0 + ms * 16 + kg * 4 + v;
                const bool lo = (m < mb);
                const int i = lo ? (m - h0 * 513) : (m - mb);
                const float val = (acc[ms][ns][v] + wcv[ms][v] * tv)
                                  * xhT[(size_t)i * B_SZ + ncol];
                if (lo) s0 += val; else s1 += val;
            }
        }
        s0 += __shfl_xor(s0, 16); s0 += __shfl_xor(s0, 32);
        if (lane < 16) atomicAdd(&y1acc[(size_t)ncol * HID + h0], s0);
        if (cross) {
            s1 += __shfl_xor(s1, 16); s1 += __shfl_xor(s1, 32);
            if (lane < 16 && (h0 + 1) < HID)
                atomicAdd(&y1acc[(size_t)ncol * HID + h0 + 1], s1);
        }
    }
}

// ---------------- MLP tail ----------------
__global__ __launch_bounds__(128) void mlp_kernel(
    const float* __restrict__ y1acc, const float* __restrict__ b1,
    const float* __restrict__ W2, const float* __restrict__ b2,
    const float* __restrict__ W3, const float* __restrict__ b3,
    float* __restrict__ out)
{
    __shared__ float y1r[HID];
    __shared__ float y2r[HID];
    const int b = blockIdx.x;
    const int h = threadIdx.x;
    y1r[h] = y1acc[(size_t)b * HID + h] + b1[h];
    __syncthreads();
    float a = b2[h];
    const float* w2r = W2 + (size_t)h * HID;
    #pragma unroll 8
    for (int k = 0; k < HID; ++k) a += w2r[k] * y1r[k];
    y2r[h] = tanhf(a);
    __syncthreads();
    if (h < OUT_SZ) {
        float a3 = b3[h];
        const float* w3r = W3 + (size_t)h * HID;
        #pragma unroll 8
        for (int k = 0; k < HID; ++k) a3 += w3r[k] * y2r[k];
        out[(size_t)b * OUT_SZ + h] = fmaxf(a3, 0.f);
    }
}

extern "C" void kernel_launch(void* const* d_in, const int* in_sizes, int n_in,
                              void* d_out, int out_size, void* d_ws, size_t ws_size,
                              hipStream_t stream) {
    const float* img = (const float*)d_in[0];
    const float* tab = (const float*)d_in[1];
    const float* W1  = (const float*)d_in[2];
    const float* b1  = (const float*)d_in[3];
    const float* W2  = (const float*)d_in[4];
    const float* b2  = (const float*)d_in[5];
    const float* W3  = (const float*)d_in[6];
    const float* b3  = (const float*)d_in[7];
    float* out = (float*)d_out;

    char* ws = (char*)d_ws;
    float*          y1acc = (float*)ws;                        // 524288 B
    unsigned short* tbt   = (unsigned short*)(ws + 524288);    // 1048576 B
    float*          xhT   = (float*)(ws + 1572864);            // 2101248 B (513x1024)
    float*          tc    = (float*)(ws + 3674112);            // 4096 B
    float*          wrowT = (float*)(ws + 3678208);            // 262656 B (513x128)
    unsigned short* w1c   = (unsigned short*)(ws + 3940864);   // 67108864 B (65536x512)
    const size_t need = 3940864ULL + 67108864ULL;

    hipMemsetAsync(y1acc, 0, (size_t)B_SZ * HID * sizeof(float), stream);
    prep_kernel<<<dim3(1024), dim3(256), 0, stream>>>(img, tab, tbt, xhT, tc);
    if (ws_size >= need) {
        prep2_kernel<<<dim3(M2 * 64 / 256), dim3(256), 0, stream>>>(W1, w1c);
        prep3_kernel<<<dim3(257), dim3(256), 0, stream>>>(W1, wrowT);
        gemm_fused<<<dim3(2048), dim3(512), 0, stream>>>(W1, w1c, tbt, xhT, tc, y1acc);
        tail_kernel<<<dim3(256), dim3(128), 0, stream>>>(img, tab, wrowT, y1acc);
    } else {
        gemm_fused_fb<<<dim3(2052), dim3(512), 0, stream>>>(W1, tbt, xhT, tc, y1acc);
    }
    mlp_kernel<<<dim3(1024), dim3(128), 0, stream>>>(y1acc, b1, W2, b2, W3, b3, out);
}

// Round 10
// 194.452 us; speedup vs baseline: 1.2310x; 1.1116x over previous
//
#include <hip/hip_runtime.h>
#include <hip/hip_bf16.h>

typedef __bf16 bf16x8 __attribute__((ext_vector_type(8)));
typedef float f32x4 __attribute__((ext_vector_type(4)));
typedef float f32x4u __attribute__((ext_vector_type(4), aligned(4)));
typedef unsigned short u16x8 __attribute__((ext_vector_type(8)));

typedef __attribute__((address_space(1))) const unsigned int gu32;
typedef __attribute__((address_space(3))) unsigned int lu32;

#define B_SZ   1024
#define IN_SZ  512
#define HID    128
#define OUT_SZ 64
#define BK     32
#define NKT    16        // K main loop = 512
#define M2     65536     // 128 h x 512 i   (main GEMM M, power of 2)

static __device__ __forceinline__ unsigned short f2bf(float f) {
    __hip_bfloat16 h = __float2bfloat16(f);
    return *reinterpret_cast<unsigned short*>(&h);
}

// ---------------- prep: t_hat bf16 [1024][512], tc, xhT [513][1024] --------
__global__ __launch_bounds__(256) void prep_kernel(
    const float* __restrict__ img, const float* __restrict__ tab,
    unsigned short* __restrict__ tbt, float* __restrict__ xhT,
    float* __restrict__ tc)
{
    const int blk = blockIdx.x;   // 0..1023
    for (int j = threadIdx.x; j < 512; j += 256) {
        float v = (j == 0) ? 1.0f : tab[(size_t)blk * IN_SZ + (j - 1)];
        tbt[(size_t)blk * 512 + j] = f2bf(v);
    }
    if (threadIdx.x == 0) tc[blk] = tab[(size_t)blk * IN_SZ + 511];
    if (blk < 513) {
        for (int b = threadIdx.x; b < B_SZ; b += 256)
            xhT[(size_t)blk * B_SZ + b] =
                (blk == 0) ? 1.0f : img[(size_t)b * IN_SZ + (blk - 1)];
    }
}

// -------- prep3: wrowT[j][h] = W1[(h*513+512)*513 + j]  (513 x 128 f32) ----
__global__ __launch_bounds__(256) void prep3_kernel(
    const float* __restrict__ w1, float* __restrict__ wrowT)
{
    const int idx = blockIdx.x * 256 + threadIdx.x;
    if (idx < 513 * 128) {
        const int j = idx >> 7, h = idx & 127;
        wrowT[idx] = w1[((size_t)h * 513 + 512) * 513 + j];
    }
}

// ---------------- main fused GEMM: in-kernel fp32->bf16 A staging ----------
// BM=128, BN=256, BK=32. 8 waves (2M x 4N), wave-tile 64x64.
// A: reg-staged (global fp32 -> cvt -> swizzled ds_write), B: gload_lds.
// 3-buf LDS, counted vmcnt, XCD swizzle; grid 2048 = exactly 4 gens.
__global__ __launch_bounds__(512, 4) void gemm_fused(
    const float* __restrict__ w1, const unsigned short* __restrict__ tbt,
    const float* __restrict__ xhT, const float* __restrict__ tc,
    float* __restrict__ y1acc)
{
    __shared__ unsigned short Als[3][128 * BK];   // 3 x 8 KB
    __shared__ unsigned short Bls[3][256 * BK];   // 3 x 16 KB

    // T1: XCD swizzle, nwg=2048 (%8==0 -> simple bijective chunking)
    const int wgid = (blockIdx.x & 7) * 256 + (blockIdx.x >> 3);
    const int bm = wgid >> 2;             // 0..511
    const int bn = wgid & 3;              // 0..3
    const int n0 = bn * 256;
    const int h0    = bm >> 2;            // block fully inside one h
    const int ibase = (bm & 3) * 128;
    const int tid  = threadIdx.x;
    const int wv   = tid >> 6;
    const int wr   = wv >> 2;             // 0..1
    const int wc   = wv & 3;              // 0..3
    const int lane = tid & 63;
    const int l15  = lane & 15;
    const int kg   = lane >> 4;

    // A staging: thread owns phys chunk p = tid; logical chunk pre-swizzled.
    // Source is W1 fp32 directly: row (h0*513 + ibase + r), 8 floats at cl*8.
    const int ar  = tid >> 2;
    const int acl = (tid & 3) ^ ((ar >> 1) & 3);
    const float* asrcF = w1 + ((size_t)h0 * 513 + ibase + ar) * 513 + acl * 8;

    // B staging: phys chunks p = tid, 512+tid (256 rows x 4 chunks)
    const unsigned short* bsrc[2];
    int bBase[2];
    #pragma unroll
    for (int q = 0; q < 2; ++q) {
        const int p  = q * 512 + tid;
        const int r  = p >> 2;
        const int cl = (p & 3) ^ ((r >> 1) & 3);
        bsrc[q] = tbt + (size_t)(n0 + r) * 512 + cl * 8;
        bBase[q] = (q * 512 + wv * 64) * 8;
    }

    // fragment read offsets (u16 units); phys chunk = kg ^ ((r>>1)&3)
    int aoffs[4], boffs[4];
    #pragma unroll
    for (int ms = 0; ms < 4; ++ms) {
        const int r = wr * 64 + ms * 16 + l15;
        aoffs[ms] = (r * 4 + (kg ^ ((r >> 1) & 3))) * 8;
    }
    #pragma unroll
    for (int ns = 0; ns < 4; ++ns) {
        const int r = wc * 64 + ns * 16 + l15;
        boffs[ns] = (r * 4 + (kg ^ ((r >> 1) & 3))) * 8;
    }

    f32x4 acc[4][4] = {};
    f32x4u rAlo, rAhi;   // single in-flight A slot (tile kt+2 data)

#define STB(BUF, KT) do {                                                    \
        const int k32_ = (KT) * BK;                                          \
        _Pragma("unroll")                                                    \
        for (int q_ = 0; q_ < 2; ++q_)                                       \
            __builtin_amdgcn_global_load_lds(                                \
                (gu32*)(const void*)(bsrc[q_] + k32_),                       \
                (lu32*)(void*)&Bls[BUF][bBase[q_]], 16, 0, 0);               \
    } while (0)
#define CVW8(DST, LO, HI) do {                                               \
        u16x8 u_;                                                            \
        u_[0] = f2bf((LO)[0]); u_[1] = f2bf((LO)[1]);                        \
        u_[2] = f2bf((LO)[2]); u_[3] = f2bf((LO)[3]);                        \
        u_[4] = f2bf((HI)[0]); u_[5] = f2bf((HI)[1]);                        \
        u_[6] = f2bf((HI)[2]); u_[7] = f2bf((HI)[3]);                        \
        *reinterpret_cast<u16x8*>(DST) = u_;                                 \
    } while (0)

    // ---- prologue: A(0),A(1) via temps; B(0),B(1) in flight ----
    {
        const f32x4u t0lo = *reinterpret_cast<const f32x4u*>(asrcF);
        const f32x4u t0hi = *reinterpret_cast<const f32x4u*>(asrcF + 4);
        const f32x4u t1lo = *reinterpret_cast<const f32x4u*>(asrcF + 32);
        const f32x4u t1hi = *reinterpret_cast<const f32x4u*>(asrcF + 36);
        CVW8(&Als[0][tid * 8], t0lo, t0hi);
        CVW8(&Als[1][tid * 8], t1lo, t1hi);
        STB(0, 0);
        STB(1, 1);
    }
    __syncthreads();

    #pragma unroll
    for (int kt = 0; kt < NKT; ++kt) {
        const int cur = kt % 3;
        const unsigned short* ab = &Als[cur][0];
        const unsigned short* bb = &Bls[cur][0];

        // write A(kt+1) from rA (loaded one iteration ago), then reload rA
        if (kt >= 1 && kt + 1 < NKT)
            CVW8(&Als[(kt + 1) % 3][tid * 8], rAlo, rAhi);
        if (kt + 2 < NKT) {
            const float* s_ = asrcF + (kt + 2) * 32;
            rAlo = *reinterpret_cast<const f32x4u*>(s_);
            rAhi = *reinterpret_cast<const f32x4u*>(s_ + 4);
        }

        bf16x8 af[4];
        #pragma unroll
        for (int ms = 0; ms < 4; ++ms)
            af[ms] = *reinterpret_cast<const bf16x8*>(&ab[aoffs[ms]]);
        __builtin_amdgcn_s_setprio(1);
        #pragma unroll
        for (int ns = 0; ns < 4; ++ns) {
            const bf16x8 bf = *reinterpret_cast<const bf16x8*>(&bb[boffs[ns]]);
            #pragma unroll
            for (int ms = 0; ms < 4; ++ms)
                acc[ms][ns] = __builtin_amdgcn_mfma_f32_16x16x32_bf16(
                    af[ms], bf, acc[ms][ns], 0, 0, 0);
        }
        __builtin_amdgcn_s_setprio(0);

        if (kt == NKT - 1) break;   // epilogue next; no more LDS handoff

        // counted wait: B(kt+1) (issued last iter, latency elapsed) must be
        // done; this iter's A loads (>=2 instrs, issued after it) excluded.
        if (kt + 2 >= NKT) asm volatile("s_waitcnt vmcnt(0)" ::: "memory");
        else               asm volatile("s_waitcnt vmcnt(2)" ::: "memory");
        if (kt + 2 < NKT) STB((kt + 2) % 3, kt + 2);
        asm volatile("s_waitcnt lgkmcnt(0)" ::: "memory");
        __builtin_amdgcn_s_barrier();
        __builtin_amdgcn_sched_barrier(0);
    }
#undef STB
#undef CVW8

    // ---- epilogue: + j=512 rank-1 term (fp32), reduce over i, one atomic --
    const size_t orow = (size_t)h0 * 513;
    float wcv[4][4];
    #pragma unroll
    for (int ms = 0; ms < 4; ++ms)
        #pragma unroll
        for (int v = 0; v < 4; ++v) {
            const int i_ = ibase + wr * 64 + ms * 16 + kg * 4 + v;
            wcv[ms][v] = w1[(orow + i_) * 513 + 512];
        }

    #pragma unroll
    for (int ns = 0; ns < 4; ++ns) {
        const int ncol = n0 + wc * 64 + ns * 16 + l15;
        const float tv = tc[ncol];
        float s0 = 0.f;
        #pragma unroll
        for (int ms = 0; ms < 4; ++ms) {
            const int i_ = ibase + wr * 64 + ms * 16 + kg * 4;
            #pragma unroll
            for (int v = 0; v < 4; ++v)
                s0 += (acc[ms][ns][v] + wcv[ms][v] * tv)
                      * xhT[(size_t)(i_ + v) * B_SZ + ncol];
        }
        s0 += __shfl_xor(s0, 16); s0 += __shfl_xor(s0, 32);
        if (lane < 16) atomicAdd(&y1acc[(size_t)ncol * HID + h0], s0);
    }
}

// -------- tail: y1acc[n,h] += x_hat[n,512] * sum_{j<=512} wrowT[j][h]*t_hat --
__global__ __launch_bounds__(128) void tail_kernel(
    const float* __restrict__ img, const float* __restrict__ tab,
    const float* __restrict__ wrowT, float* __restrict__ y1acc)
{
    __shared__ float tls[4][513];
    const int b0 = blockIdx.x * 4;
    const int h  = threadIdx.x;
    #pragma unroll
    for (int q = 0; q < 4; ++q)
        for (int j = h; j < 513; j += 128)
            tls[q][j] = (j == 0) ? 1.0f : tab[(size_t)(b0 + q) * IN_SZ + (j - 1)];
    __syncthreads();
    float a0 = 0.f, a1 = 0.f, a2 = 0.f, a3 = 0.f;
    #pragma unroll 8
    for (int j = 0; j < 513; ++j) {
        const float w = wrowT[j * 128 + h];
        a0 += w * tls[0][j]; a1 += w * tls[1][j];
        a2 += w * tls[2][j]; a3 += w * tls[3][j];
    }
    atomicAdd(&y1acc[(size_t)(b0 + 0) * HID + h], a0 * img[(size_t)(b0 + 0) * IN_SZ + 511]);
    atomicAdd(&y1acc[(size_t)(b0 + 1) * HID + h], a1 * img[(size_t)(b0 + 1) * IN_SZ + 511]);
    atomicAdd(&y1acc[(size_t)(b0 + 2) * HID + h], a2 * img[(size_t)(b0 + 2) * IN_SZ + 511]);
    atomicAdd(&y1acc[(size_t)(b0 + 3) * HID + h], a3 * img[(size_t)(b0 + 3) * IN_SZ + 511]);
}

// ---------------- fallback GEMM (fp32-A path, 513-K, needs only small ws) ---
__global__ __launch_bounds__(512, 4) void gemm_fused_fb(
    const float* __restrict__ w1, const unsigned short* __restrict__ tbt,
    const float* __restrict__ xhT, const float* __restrict__ tc,
    float* __restrict__ y1acc)
{
    __shared__ float          Afs[2][64 * BK];
    __shared__ unsigned short Bls[2][512 * BK];

    const int bm = blockIdx.x >> 1;
    const int bn = blockIdx.x & 1;
    const int m0 = bm * 64;
    const int n0 = bn * 512;
    const int tid  = threadIdx.x;
    const int wv   = tid >> 6;
    const int lane = tid & 63;
    const int l15  = lane & 15;
    const int kg   = lane >> 4;

    const int ar  = tid >> 3;
    const int acl = (tid & 7) ^ (ar & 7);
    const float* asrc = w1 + (size_t)(m0 + ar) * 513 + acl * 4;
    const int aBase = (wv * 64) * 4;

    const unsigned short* bsrc[4];
    int bBase[4];
    #pragma unroll
    for (int q = 0; q < 4; ++q) {
        const int p  = q * 512 + tid;
        const int r  = p >> 2;
        const int cl = (p & 3) ^ ((r >> 1) & 3);
        bsrc[q] = tbt + (size_t)(n0 + r) * 512 + cl * 8;
        bBase[q] = (q * 512 + wv * 64) * 8;
    }

    int aoff0[4], aoff1[4], boffs[4];
    #pragma unroll
    for (int ms = 0; ms < 4; ++ms) {
        const int r = ms * 16 + l15;
        aoff0[ms] = r * 32 + (((kg * 2) + 0) ^ (r & 7)) * 4;
        aoff1[ms] = r * 32 + (((kg * 2) + 1) ^ (r & 7)) * 4;
    }
    #pragma unroll
    for (int ns = 0; ns < 4; ++ns) {
        const int r = wv * 64 + ns * 16 + l15;
        boffs[ns] = ((r << 2) | (kg ^ ((r >> 1) & 3))) * 8;
    }

    f32x4 acc[4][4] = {};

#define STAGE_FB(BUF, KT) do {                                               \
        const int k32_ = (KT) * BK;                                          \
        _Pragma("unroll")                                                    \
        for (int q_ = 0; q_ < 4; ++q_)                                       \
            __builtin_amdgcn_global_load_lds(                                \
                (gu32*)(const void*)(bsrc[q_] + k32_),                       \
                (lu32*)(void*)&Bls[BUF][bBase[q_]], 16, 0, 0);               \
        __builtin_amdgcn_global_load_lds(                                    \
            (gu32*)(const void*)(asrc + k32_),                               \
            (lu32*)(void*)&Afs[BUF][aBase], 16, 0, 0);                       \
    } while (0)

    STAGE_FB(0, 0);
    __syncthreads();

    for (int kt = 0; kt < NKT; ++kt) {
        const int cur = kt & 1;
        if (kt + 1 < NKT) STAGE_FB(cur ^ 1, kt + 1);

        const float*          ab = &Afs[cur][0];
        const unsigned short* bb = &Bls[cur][0];
        bf16x8 bfr[4];
        #pragma unroll
        for (int ns = 0; ns < 4; ++ns)
            bfr[ns] = *reinterpret_cast<const bf16x8*>(&bb[boffs[ns]]);
        #pragma unroll
        for (int ms = 0; ms < 4; ++ms) {
            const f32x4 lo = *reinterpret_cast<const f32x4*>(&ab[aoff0[ms]]);
            const f32x4 hi = *reinterpret_cast<const f32x4*>(&ab[aoff1[ms]]);
            u16x8 u;
            u[0] = f2bf(lo[0]); u[1] = f2bf(lo[1]);
            u[2] = f2bf(lo[2]); u[3] = f2bf(lo[3]);
            u[4] = f2bf(hi[0]); u[5] = f2bf(hi[1]);
            u[6] = f2bf(hi[2]); u[7] = f2bf(hi[3]);
            const bf16x8 af = __builtin_bit_cast(bf16x8, u);
            #pragma unroll
            for (int ns = 0; ns < 4; ++ns)
                acc[ms][ns] = __builtin_amdgcn_mfma_f32_16x16x32_bf16(
                    af, bfr[ns], acc[ms][ns], 0, 0, 0);
        }
        __syncthreads();
    }
#undef STAGE_FB

    const int h0 = m0 / 513;
    const int mb = (h0 + 1) * 513;
    const bool cross = (mb < m0 + 64);

    float wcv[4][4];
    #pragma unroll
    for (int ms = 0; ms < 4; ++ms)
        #pragma unroll
        for (int v = 0; v < 4; ++v)
            wcv[ms][v] = w1[(size_t)(m0 + ms * 16 + kg * 4 + v) * 513 + 512];

    #pragma unroll
    for (int ns = 0; ns < 4; ++ns) {
        const int ncol = n0 + wv * 64 + ns * 16 + l15;
        const float tv = tc[ncol];
        float s0 = 0.f, s1 = 0.f;
        #pragma unroll
        for (int ms = 0; ms < 4; ++ms) {
            #pragma unroll
            for (int v = 0; v < 4; ++v) {
                const int m = m0 + ms * 16 + kg * 4 + v;
                const bool lo = (m < mb);
                const int i = lo ? (m - h0 * 513) : (m - mb);
                const float val = (acc[ms][ns][v] + wcv[ms][v] * tv)
                                  * xhT[(size_t)i * B_SZ + ncol];
                if (lo) s0 += val; else s1 += val;
            }
        }
        s0 += __shfl_xor(s0, 16); s0 += __shfl_xor(s0, 32);
        if (lane < 16) atomicAdd(&y1acc[(size_t)ncol * HID + h0], s0);
        if (cross) {
            s1 += __shfl_xor(s1, 16); s1 += __shfl_xor(s1, 32);
            if (lane < 16 && (h0 + 1) < HID)
                atomicAdd(&y1acc[(size_t)ncol * HID + h0 + 1], s1);
        }
    }
}

// ---------------- MLP tail ----------------
__global__ __launch_bounds__(128) void mlp_kernel(
    const float* __restrict__ y1acc, const float* __restrict__ b1,
    const float* __restrict__ W2, const float* __restrict__ b2,
    const float* __restrict__ W3, const float* __restrict__ b3,
    float* __restrict__ out)
{
    __shared__ float y1r[HID];
    __shared__ float y2r[HID];
    const int b = blockIdx.x;
    const int h = threadIdx.x;
    y1r[h] = y1acc[(size_t)b * HID + h] + b1[h];
    __syncthreads();
    float a = b2[h];
    const float* w2r = W2 + (size_t)h * HID;
    #pragma unroll 8
    for (int k = 0; k < HID; ++k) a += w2r[k] * y1r[k];
    y2r[h] = tanhf(a);
    __syncthreads();
    if (h < OUT_SZ) {
        float a3 = b3[h];
        const float* w3r = W3 + (size_t)h * HID;
        #pragma unroll 8
        for (int k = 0; k < HID; ++k) a3 += w3r[k] * y2r[k];
        out[(size_t)b * OUT_SZ + h] = fmaxf(a3, 0.f);
    }
}

extern "C" void kernel_launch(void* const* d_in, const int* in_sizes, int n_in,
                              void* d_out, int out_size, void* d_ws, size_t ws_size,
                              hipStream_t stream) {
    const float* img = (const float*)d_in[0];
    const float* tab = (const float*)d_in[1];
    const float* W1  = (const float*)d_in[2];
    const float* b1  = (const float*)d_in[3];
    const float* W2  = (const float*)d_in[4];
    const float* b2  = (const float*)d_in[5];
    const float* W3  = (const float*)d_in[6];
    const float* b3  = (const float*)d_in[7];
    float* out = (float*)d_out;

    char* ws = (char*)d_ws;
    float*          y1acc = (float*)ws;                        // 524288 B
    unsigned short* tbt   = (unsigned short*)(ws + 524288);    // 1048576 B
    float*          xhT   = (float*)(ws + 1572864);            // 2101248 B (513x1024)
    float*          tc    = (float*)(ws + 3674112);            // 4096 B
    float*          wrowT = (float*)(ws + 3678208);            // 262656 B (513x128)
    const size_t need = 3678208ULL + 262656ULL;

    hipMemsetAsync(y1acc, 0, (size_t)B_SZ * HID * sizeof(float), stream);
    prep_kernel<<<dim3(1024), dim3(256), 0, stream>>>(img, tab, tbt, xhT, tc);
    if (ws_size >= need) {
        prep3_kernel<<<dim3(257), dim3(256), 0, stream>>>(W1, wrowT);
        gemm_fused<<<dim3(2048), dim3(512), 0, stream>>>(W1, tbt, xhT, tc, y1acc);
        tail_kernel<<<dim3(256), dim3(128), 0, stream>>>(img, tab, wrowT, y1acc);
    } else {
        gemm_fused_fb<<<dim3(2052), dim3(512), 0, stream>>>(W1, tbt, xhT, tc, y1acc);
    }
    mlp_kernel<<<dim3(1024), dim3(128), 0, stream>>>(y1acc, b1, W2, b2, W3, b3, out);
}